// Round 12
// baseline (346.866 us; speedup 1.0000x reference)
//
#include <hip/hip_runtime.h>
#include <math.h>

#define NB 4
#define NT 2048
#define NC 1024
#define NHEADS 16
#define HDIM 64

typedef __attribute__((ext_vector_type(8))) _Float16 half8v;
typedef __attribute__((ext_vector_type(2))) __fp16 fp16x2;
typedef __attribute__((ext_vector_type(4))) float f32x4;

#define LOG2E 1.4426950408889634f

__device__ inline unsigned short f2h(float f) {
    _Float16 h = (_Float16)f;
    return __builtin_bit_cast(unsigned short, h);
}
__device__ inline float h2f(unsigned short u) {
    return (float)__builtin_bit_cast(_Float16, u);
}
__device__ inline float exp2fast(float x) {
#if __has_builtin(__builtin_amdgcn_exp2f)
    return __builtin_amdgcn_exp2f(x);
#else
    return exp2f(x);
#endif
}
__device__ inline unsigned int pack2h(float a, float b) {
    fp16x2 p = __builtin_amdgcn_cvt_pkrtz(a, b);
    return __builtin_bit_cast(unsigned int, p);
}

#define AS1C(p) ((const __attribute__((address_space(1))) unsigned int*)(unsigned long long)(const void*)(p))
#define AS3P(p) ((__attribute__((address_space(3))) unsigned int*)(unsigned int)(unsigned long long)(void*)(p))
#define GLL16(gp, lp) __builtin_amdgcn_global_load_lds(AS1C(gp), AS3P(lp), 16, 0, 0)

// ---------------------------------------------------------------------------
// fp32 -> fp16 convert (vectorized)
// ---------------------------------------------------------------------------
__global__ __launch_bounds__(256) void conv_f16_kernel(
    const float* __restrict__ in, unsigned short* __restrict__ out, int n4)
{
    const int i = blockIdx.x * 256 + threadIdx.x;
    if (i >= n4) return;
    const float4 f = ((const float4*)in)[i];
    ushort4 h;
    h.x = f2h(f.x); h.y = f2h(f.y); h.z = f2h(f.z); h.w = f2h(f.w);
    ((ushort4*)out)[i] = h;
}

// ---------------------------------------------------------------------------
// mask fp32 -> fp16 * log2e, permuted into MFMA fragment order per 64-col
// block: out[row][kt*64 + fr*4 + nt] = in[row][kt*64 + nt*16 + fr] * log2e
// ---------------------------------------------------------------------------
__global__ __launch_bounds__(256) void mask_conv_kernel(
    const float* __restrict__ in, unsigned short* __restrict__ out)
{
    const size_t i = (size_t)blockIdx.x * 256 + threadIdx.x;  // ushort4 index
    const int row = (int)(i >> 9);
    const int c4 = (int)(i & 511);
    const int ktb = c4 >> 4;
    const int fr = c4 & 15;
    const float* ip = in + (size_t)row * NT + ktb * 64 + fr;
    ushort4 o;
    o.x = f2h(ip[0] * LOG2E);
    o.y = f2h(ip[16] * LOG2E);
    o.z = f2h(ip[32] * LOG2E);
    o.w = f2h(ip[48] * LOG2E);
    ((ushort4*)out)[i] = o;
}

// ---------------------------------------------------------------------------
// Kernel 1: qkv = x @ w^T + b via fp16 MFMA, fused RoPE.
// q written fp16 (B,NH,T,D) PRE-SCALED by scl*log2e; k fp16 (B,NH,T,D);
// v written TRANSPOSED+key-PERMUTED fp16: vt2[b][h][d][(t&~63) + pi(t&63)]
// with pi(nt*16+fr) = fr*4+nt, matching attention's P/V k-ordering.
// ---------------------------------------------------------------------------
__global__ __launch_bounds__(256) void qkv_gemm_kernel(
    const unsigned short* __restrict__ xf, const unsigned short* __restrict__ wf,
    const float* __restrict__ bias, const float* __restrict__ pe_cos,
    const float* __restrict__ pe_sin, const float* __restrict__ pe_scale,
    unsigned short* __restrict__ qb, unsigned short* __restrict__ kb,
    unsigned short* __restrict__ vtb)
{
    __shared__ __align__(16) unsigned short Ah[128 * 32];
    __shared__ __align__(16) unsigned short Bh[128 * 32];

    const int tid = threadIdx.x;
    const int w = tid >> 6, lane = tid & 63;
    const int g = lane >> 4, fr = lane & 15;
    const int wr = w >> 1, wc = w & 1;

    const int bid = blockIdx.x;                 // 1536 blocks, XCD swizzle
    const int s = (bid & 7) * 192 + (bid >> 3);
    const int m0 = (s & 63) * 128, n0 = (s >> 6) * 128;

    const int c0 = tid, c1 = tid + 256;
    const int r0 = c0 >> 2, r1 = c1 >> 2;
    const int cb0 = ((c0 & 3) * 16) ^ (((r0 >> 1) & 3) << 4);
    const int cb1 = ((c1 & 3) * 16) ^ (((r1 >> 1) & 3) << 4);
    const unsigned short* px0 = xf + (size_t)(m0 + r0) * NC + (cb0 >> 1);
    const unsigned short* px1 = xf + (size_t)(m0 + r1) * NC + (cb1 >> 1);
    const unsigned short* pw0 = wf + (size_t)(n0 + r0) * NC + (cb0 >> 1);
    const unsigned short* pw1 = wf + (size_t)(n0 + r1) * NC + (cb1 >> 1);

    f32x4 acc[4][4];
#pragma unroll
    for (int m = 0; m < 4; ++m)
#pragma unroll
        for (int n = 0; n < 4; ++n) acc[m][n] = (f32x4){0.f, 0.f, 0.f, 0.f};

    for (int k0 = 0; k0 < NC; k0 += 32) {
        __syncthreads();
        GLL16(px0 + k0, (char*)Ah + c0 * 16);
        GLL16(px1 + k0, (char*)Ah + c1 * 16);
        GLL16(pw0 + k0, (char*)Bh + c0 * 16);
        GLL16(pw1 + k0, (char*)Bh + c1 * 16);
        __syncthreads();

        half8v a_f[4], b_f[4];
#pragma unroll
        for (int m = 0; m < 4; ++m) {
            const int r = wr * 64 + m * 16 + fr;
            const int off = r * 64 + ((g * 16) ^ (((r >> 1) & 3) << 4));
            a_f[m] = *(const half8v*)((const char*)Ah + off);
        }
#pragma unroll
        for (int n = 0; n < 4; ++n) {
            const int r = wc * 64 + n * 16 + fr;
            const int off = r * 64 + ((g * 16) ^ (((r >> 1) & 3) << 4));
            b_f[n] = *(const half8v*)((const char*)Bh + off);
        }
#pragma unroll
        for (int m = 0; m < 4; ++m)
#pragma unroll
            for (int n = 0; n < 4; ++n)
                acc[m][n] = __builtin_amdgcn_mfma_f32_16x16x32_f16(a_f[m], b_f[n], acc[m][n], 0, 0, 0);
    }

    // Epilogue: bias + RoPE (+*scale*scl*log2e q, /scale k), scatter.
    const float QSCL = 0.08838834764831845f * LOG2E;  // 1/sqrt(2*D) * log2e
#pragma unroll
    for (int n = 0; n < 4; ++n) {
        const int col = n0 + wc * 64 + n * 16 + fr;
        const int part = col >> 10;             // wave-uniform (16-col span)
        const int hh = (col & 1023) >> 6;
        const int dd = col & 63;
        const float bv = bias[col];
        if (part < 2) {
            unsigned short* outp = (part == 0) ? qb : kb;
#pragma unroll
            for (int m = 0; m < 4; ++m) {
                const int row0 = m0 + wr * 64 + m * 16 + 4 * g;
                const int bb = row0 >> 11;
                const int t0 = row0 & 2047;
#pragma unroll
                for (int j = 0; j < 4; ++j) {
                    const int t = t0 + j;
                    float val = acc[m][n][j] + bv;
                    const float partner = __shfl_xor(val, 1, 64);
                    const int pidx = t * HDIM + dd;
                    const float cc = pe_cos[pidx], ss = pe_sin[pidx], sc = pe_scale[pidx];
                    const float r = (dd & 1) ? (val * cc + partner * ss)
                                             : (val * cc - partner * ss);
                    val = (part == 0) ? (r * sc * QSCL) : (r / sc);
                    outp[(((size_t)bb * NHEADS + hh) * NT + t) * HDIM + dd] = f2h(val);
                }
            }
        } else {
            // v: key-permuted transpose. Thread holds keys {nt=m, fr'=4g+j}
            // across m -> pos (4g+j)*4 + m are 4 consecutive -> ushort4.
            const int rowb = m0 + wr * 64;       // 64-aligned
            const int bb = rowb >> 11;
            const int tb = rowb & 2047;
            unsigned short* vp2 =
                &vtb[(((size_t)bb * NHEADS + hh) * HDIM + dd) * NT + tb];
#pragma unroll
            for (int j = 0; j < 4; ++j) {
                ushort4 sv;
                sv.x = f2h(acc[0][n][j] + bv);
                sv.y = f2h(acc[1][n][j] + bv);
                sv.z = f2h(acc[2][n][j] + bv);
                sv.w = f2h(acc[3][n][j] + bv);
                *(ushort4*)&vp2[(4 * g + j) * 4] = sv;
            }
        }
    }
}

// ---------------------------------------------------------------------------
// Kernel 2: flash attention, fp16 MFMA. 1 block = (b,h,256 q-rows), 4 waves,
// each wave 64 q-rows (M=4 m-tiles) -> K/V fragment reads amortized 2x vs
// M=2 (LDS-throughput-bound regime). Plain launch_bounds (NO register cap
// -- round 6's spill was the forced cap). mi is per-m tile-wide (reg diet).
// K/Vt double-buffered; PV per m-tile; exp2-folded; pi-permuted key axis.
// ---------------------------------------------------------------------------
__global__ __launch_bounds__(256) void attn_mfma_kernel(
    const unsigned short* __restrict__ qb, const unsigned short* __restrict__ kb,
    const unsigned short* __restrict__ vtb, const unsigned short* __restrict__ m16,
    float* __restrict__ out)
{
    __shared__ __align__(16) unsigned short Ks[2][64 * 64];
    __shared__ __align__(16) unsigned short Vs[2][64 * 64];
    __shared__ __align__(16) unsigned short Ps[4][16 * 64];

    const int tid = threadIdx.x;
    const int w = tid >> 6, lane = tid & 63;
    const int g = lane >> 4, fr = lane & 15;

    const int bid = blockIdx.x;                  // 512 blocks, XCD swizzle
    const int s = (bid & 7) * 64 + (bid >> 3);
    const int q0 = (s & 7) * 256;
    const int h = (s >> 3) & 15;
    const int b = s >> 7;

    const size_t bh = (size_t)b * NHEADS + h;
    const unsigned short* qp = qb + (bh * NT + q0 + w * 64) * HDIM;
    const unsigned short* kp = kb + bh * NT * HDIM;
    const unsigned short* vtp = vtb + bh * HDIM * NT;
    const unsigned short* mp = m16 + ((size_t)b * NT + q0 + w * 64) * NT;

    const int sc0 = tid, sc1 = tid + 256;
    const int sr0 = sc0 >> 3, scb0 = ((sc0 & 7) * 16) ^ ((sr0 & 7) << 4);
    const int sr1 = sc1 >> 3, scb1 = ((sc1 & 7) * 16) ^ ((sr1 & 7) << 4);

#define STAGE(buf, kt)                                                          \
    do {                                                                        \
        const unsigned short* ktp_ = kp + (kt) * 64 * HDIM;                     \
        GLL16(ktp_ + sr0 * HDIM + (scb0 >> 1), (char*)Ks[buf] + sc0 * 16);      \
        GLL16(vtp + (size_t)sr0 * NT + (kt) * 64 + (scb0 >> 1),                 \
              (char*)Vs[buf] + sc0 * 16);                                       \
        GLL16(ktp_ + sr1 * HDIM + (scb1 >> 1), (char*)Ks[buf] + sc1 * 16);      \
        GLL16(vtp + (size_t)sr1 * NT + (kt) * 64 + (scb1 >> 1),                 \
              (char*)Vs[buf] + sc1 * 16);                                       \
    } while (0)

    half8v qf[4][2];
#pragma unroll
    for (int m = 0; m < 4; ++m)
#pragma unroll
        for (int kk = 0; kk < 2; ++kk)
            qf[m][kk] = *(const half8v*)(qp + (m * 16 + fr) * HDIM + kk * 32 + g * 8);

    f32x4 acc[4][4];
    float li[4][4], mi[4];
#pragma unroll
    for (int m = 0; m < 4; ++m) {
        mi[m] = -3.0e38f;
#pragma unroll
        for (int j = 0; j < 4; ++j) {
            li[m][j] = 0.f;
            acc[m][j] = (f32x4){0.f, 0.f, 0.f, 0.f};
        }
    }
    const float THR = 11.541560327111708f;   // 8 * log2e

    STAGE(0, 0);
    __syncthreads();
    int cur = 0;

    for (int kt = 0; kt < NT / 64; ++kt) {
        if (kt + 1 < NT / 64) STAGE(cur ^ 1, kt + 1);

        // K and V fragments once per tile, reused by all 4 m-tiles
        half8v kf[4][2], vf[4][2];
#pragma unroll
        for (int nt = 0; nt < 4; ++nt) {
            const int r = nt * 16 + fr;
#pragma unroll
            for (int kk = 0; kk < 2; ++kk) {
                const int off = r * 128 + ((kk * 64 + g * 16) ^ ((r & 7) << 4));
                kf[nt][kk] = *(const half8v*)((const char*)Ks[cur] + off);
                vf[nt][kk] = *(const half8v*)((const char*)Vs[cur] + off);
            }
        }

#pragma unroll
        for (int m = 0; m < 4; ++m) {
            f32x4 Sm[4];
#pragma unroll
            for (int nt = 0; nt < 4; ++nt) {
                Sm[nt] = (f32x4){0.f, 0.f, 0.f, 0.f};
#pragma unroll
                for (int kk = 0; kk < 2; ++kk)
                    Sm[nt] = __builtin_amdgcn_mfma_f32_16x16x32_f16(qf[m][kk], kf[nt][kk], Sm[nt], 0, 0, 0);
            }

            float sv[4][4];
            float smax = -3.4e38f;
#pragma unroll
            for (int j = 0; j < 4; ++j) {
                const ushort4 mv = *(const ushort4*)(
                    mp + (size_t)(m * 16 + 4 * g + j) * NT + kt * 64 + fr * 4);
                sv[j][0] = Sm[0][j] + h2f(mv.x);
                sv[j][1] = Sm[1][j] + h2f(mv.y);
                sv[j][2] = Sm[2][j] + h2f(mv.z);
                sv[j][3] = Sm[3][j] + h2f(mv.w);
                smax = fmaxf(smax,
                             fmaxf(fmaxf(sv[j][0], sv[j][1]),
                                   fmaxf(sv[j][2], sv[j][3])));
            }

            // defer-max: mi[m] is tile-wide; reduce only on threat
            if (!__all(smax - mi[m] <= THR)) {
                float rm = smax;
                rm = fmaxf(rm, __shfl_xor(rm, 1, 64));
                rm = fmaxf(rm, __shfl_xor(rm, 2, 64));
                rm = fmaxf(rm, __shfl_xor(rm, 4, 64));
                rm = fmaxf(rm, __shfl_xor(rm, 8, 64));
                rm = fmaxf(rm, __shfl_xor(rm, 16, 64));
                rm = fmaxf(rm, __shfl_xor(rm, 32, 64));
                const float mnew = fmaxf(mi[m], rm);
                const float alpha = exp2fast(mi[m] - mnew);
#pragma unroll
                for (int j = 0; j < 4; ++j) {
                    li[m][j] *= alpha;
#pragma unroll
                    for (int dt = 0; dt < 4; ++dt) acc[m][dt][j] *= alpha;
                }
                mi[m] = mnew;
            }

            // P into the wave's 16x64 buffer (reused across m)
#pragma unroll
            for (int j = 0; j < 4; ++j) {
                const int prow = 4 * g + j;
                const float p0 = exp2fast(sv[j][0] - mi[m]);
                const float p1 = exp2fast(sv[j][1] - mi[m]);
                const float p2 = exp2fast(sv[j][2] - mi[m]);
                const float p3 = exp2fast(sv[j][3] - mi[m]);
                li[m][j] += (p0 + p1) + (p2 + p3);
                uint2 pw2;
                pw2.x = pack2h(p0, p1);
                pw2.y = pack2h(p2, p3);
                const int off = prow * 128 + ((fr * 8) ^ ((prow & 7) << 4));
                *(uint2*)((char*)Ps[w] + off) = pw2;
            }

            // PV for this m immediately (same-wave write->read, lgkm-ordered)
            half8v pf[2];
#pragma unroll
            for (int kk = 0; kk < 2; ++kk) {
                const int off = fr * 128 + ((kk * 64 + g * 16) ^ ((fr & 7) << 4));
                pf[kk] = *(const half8v*)((const char*)Ps[w] + off);
            }
#pragma unroll
            for (int dt = 0; dt < 4; ++dt)
#pragma unroll
                for (int kk = 0; kk < 2; ++kk)
                    acc[m][dt] = __builtin_amdgcn_mfma_f32_16x16x32_f16(pf[kk], vf[dt][kk], acc[m][dt], 0, 0, 0);
        }

        __syncthreads();
        cur ^= 1;
    }

#pragma unroll
    for (int m = 0; m < 4; ++m)
#pragma unroll
        for (int j = 0; j < 4; ++j) {
            float lt = li[m][j];
            lt += __shfl_xor(lt, 1, 64);
            lt += __shfl_xor(lt, 2, 64);
            lt += __shfl_xor(lt, 4, 64);
            lt += __shfl_xor(lt, 8, 64);
            const float inv = 1.f / lt;
            const int t = q0 + w * 64 + m * 16 + 4 * g + j;
            float* op = out + (((size_t)b * NT + t) * NHEADS + h) * HDIM;
#pragma unroll
            for (int dt = 0; dt < 4; ++dt) op[dt * 16 + fr] = acc[m][dt][j] * inv;
        }
}

extern "C" void kernel_launch(void* const* d_in, const int* in_sizes, int n_in,
                              void* d_out, int out_size, void* d_ws, size_t ws_size,
                              hipStream_t stream) {
    const float* x        = (const float*)d_in[0];
    const float* pe_cos   = (const float*)d_in[1];
    const float* pe_sin   = (const float*)d_in[2];
    const float* pe_scale = (const float*)d_in[3];
    const float* mask     = (const float*)d_in[4];
    const float* w_qkv    = (const float*)d_in[5];
    const float* b_qkv    = (const float*)d_in[6];
    float* out = (float*)d_out;

    unsigned short* ws = (unsigned short*)d_ws;
    const size_t PER = (size_t)NB * NHEADS * NT * HDIM;   // 8388608
    unsigned short* qbuf = ws;
    unsigned short* kbuf = ws + PER;
    unsigned short* vtbuf = ws + 2 * PER;
    unsigned short* xbuf = ws + 3 * PER;                  // fp16 x (GEMM only)
    unsigned short* wbuf = xbuf + (size_t)NB * NT * NC;   // fp16 w (GEMM only)
    unsigned short* maskbuf = ws + 3 * PER;               // fp16 mask (after GEMM)

    conv_f16_kernel<<<8192, 256, 0, stream>>>(x, xbuf, (NB * NT * NC) / 4);
    conv_f16_kernel<<<3072, 256, 0, stream>>>(w_qkv, wbuf, (3 * NC * NC) / 4);
    qkv_gemm_kernel<<<1536, 256, 0, stream>>>(xbuf, wbuf, b_qkv,
                                              pe_cos, pe_sin, pe_scale,
                                              qbuf, kbuf, vtbuf);
    mask_conv_kernel<<<16384, 256, 0, stream>>>(mask, maskbuf);
    attn_mfma_kernel<<<512, 256, 0, stream>>>(qbuf, kbuf, vtbuf, maskbuf, out);
}

// Round 13
// 270.955 us; speedup vs baseline: 1.2802x; 1.2802x over previous
//
#include <hip/hip_runtime.h>
#include <math.h>

#define NB 4
#define NT 2048
#define NC 1024
#define NHEADS 16
#define HDIM 64

typedef __attribute__((ext_vector_type(8))) _Float16 half8v;
typedef __attribute__((ext_vector_type(2))) __fp16 fp16x2;
typedef __attribute__((ext_vector_type(4))) float f32x4;
typedef __attribute__((ext_vector_type(4))) unsigned int u32x4;

#define LOG2E 1.4426950408889634f

__device__ inline unsigned short f2h(float f) {
    _Float16 h = (_Float16)f;
    return __builtin_bit_cast(unsigned short, h);
}
__device__ inline float h2f(unsigned short u) {
    return (float)__builtin_bit_cast(_Float16, u);
}
__device__ inline float exp2fast(float x) {
#if __has_builtin(__builtin_amdgcn_exp2f)
    return __builtin_amdgcn_exp2f(x);
#else
    return exp2f(x);
#endif
}
__device__ inline unsigned int pack2h(float a, float b) {
    fp16x2 p = __builtin_amdgcn_cvt_pkrtz(a, b);
    return __builtin_bit_cast(unsigned int, p);
}

#define AS1C(p) ((const __attribute__((address_space(1))) unsigned int*)(unsigned long long)(const void*)(p))
#define AS3P(p) ((__attribute__((address_space(3))) unsigned int*)(unsigned int)(unsigned long long)(void*)(p))
#define GLL16(gp, lp) __builtin_amdgcn_global_load_lds(AS1C(gp), AS3P(lp), 16, 0, 0)

// ---------------------------------------------------------------------------
// fp32 -> fp16 convert (vectorized), optional scale
// ---------------------------------------------------------------------------
__global__ __launch_bounds__(256) void conv_f16_kernel(
    const float* __restrict__ in, unsigned short* __restrict__ out, int n4,
    float scale)
{
    const int i = blockIdx.x * 256 + threadIdx.x;
    if (i >= n4) return;
    const float4 f = ((const float4*)in)[i];
    ushort4 h;
    h.x = f2h(f.x * scale); h.y = f2h(f.y * scale);
    h.z = f2h(f.z * scale); h.w = f2h(f.w * scale);
    ((ushort4*)out)[i] = h;
}

// ---------------------------------------------------------------------------
// Kernel 1: qkv = x @ w^T + b via fp16 MFMA, fused RoPE.
// q fp16 (B,NH,T,D) PRE-SCALED by scl*log2e; k fp16 (B,NH,T,D);
// v TRANSPOSED + sigma-PERMUTED fp16: vt[b][h][d][(t&~63) + sigma(t&63)],
// sigma(nt*16 + 4g + j) = (nt&1)*32 + 8g + (nt>>1)*4 + j  -- matches the
// swapped-QK^T P fragment layout so PV needs no P LDS round-trip.
// ---------------------------------------------------------------------------
__global__ __launch_bounds__(256) void qkv_gemm_kernel(
    const unsigned short* __restrict__ xf, const unsigned short* __restrict__ wf,
    const float* __restrict__ bias, const float* __restrict__ pe_cos,
    const float* __restrict__ pe_sin, const float* __restrict__ pe_scale,
    unsigned short* __restrict__ qb, unsigned short* __restrict__ kb,
    unsigned short* __restrict__ vtb)
{
    __shared__ __align__(16) unsigned short Ah[128 * 32];
    __shared__ __align__(16) unsigned short Bh[128 * 32];

    const int tid = threadIdx.x;
    const int w = tid >> 6, lane = tid & 63;
    const int g = lane >> 4, fr = lane & 15;
    const int wr = w >> 1, wc = w & 1;

    const int bid = blockIdx.x;                 // 1536 blocks, XCD swizzle
    const int s = (bid & 7) * 192 + (bid >> 3);
    const int m0 = (s & 63) * 128, n0 = (s >> 6) * 128;

    const int c0 = tid, c1 = tid + 256;
    const int r0 = c0 >> 2, r1 = c1 >> 2;
    const int cb0 = ((c0 & 3) * 16) ^ (((r0 >> 1) & 3) << 4);
    const int cb1 = ((c1 & 3) * 16) ^ (((r1 >> 1) & 3) << 4);
    const unsigned short* px0 = xf + (size_t)(m0 + r0) * NC + (cb0 >> 1);
    const unsigned short* px1 = xf + (size_t)(m0 + r1) * NC + (cb1 >> 1);
    const unsigned short* pw0 = wf + (size_t)(n0 + r0) * NC + (cb0 >> 1);
    const unsigned short* pw1 = wf + (size_t)(n0 + r1) * NC + (cb1 >> 1);

    f32x4 acc[4][4];
#pragma unroll
    for (int m = 0; m < 4; ++m)
#pragma unroll
        for (int n = 0; n < 4; ++n) acc[m][n] = (f32x4){0.f, 0.f, 0.f, 0.f};

    for (int k0 = 0; k0 < NC; k0 += 32) {
        __syncthreads();
        GLL16(px0 + k0, (char*)Ah + c0 * 16);
        GLL16(px1 + k0, (char*)Ah + c1 * 16);
        GLL16(pw0 + k0, (char*)Bh + c0 * 16);
        GLL16(pw1 + k0, (char*)Bh + c1 * 16);
        __syncthreads();

        half8v a_f[4], b_f[4];
#pragma unroll
        for (int m = 0; m < 4; ++m) {
            const int r = wr * 64 + m * 16 + fr;
            const int off = r * 64 + ((g * 16) ^ (((r >> 1) & 3) << 4));
            a_f[m] = *(const half8v*)((const char*)Ah + off);
        }
#pragma unroll
        for (int n = 0; n < 4; ++n) {
            const int r = wc * 64 + n * 16 + fr;
            const int off = r * 64 + ((g * 16) ^ (((r >> 1) & 3) << 4));
            b_f[n] = *(const half8v*)((const char*)Bh + off);
        }
#pragma unroll
        for (int m = 0; m < 4; ++m)
#pragma unroll
            for (int n = 0; n < 4; ++n)
                acc[m][n] = __builtin_amdgcn_mfma_f32_16x16x32_f16(a_f[m], b_f[n], acc[m][n], 0, 0, 0);
    }

    // Epilogue: bias + RoPE (+*scale*scl*log2e q, /scale k), scatter.
    const float QSCL = 0.08838834764831845f * LOG2E;  // 1/sqrt(2*D) * log2e
#pragma unroll
    for (int n = 0; n < 4; ++n) {
        const int col = n0 + wc * 64 + n * 16 + fr;
        const int part = col >> 10;             // wave-uniform (16-col span)
        const int hh = (col & 1023) >> 6;
        const int dd = col & 63;
        const float bv = bias[col];
        if (part < 2) {
            unsigned short* outp = (part == 0) ? qb : kb;
#pragma unroll
            for (int m = 0; m < 4; ++m) {
                const int row0 = m0 + wr * 64 + m * 16 + 4 * g;
                const int bb = row0 >> 11;
                const int t0 = row0 & 2047;
#pragma unroll
                for (int j = 0; j < 4; ++j) {
                    const int t = t0 + j;
                    float val = acc[m][n][j] + bv;
                    const float partner = __shfl_xor(val, 1, 64);
                    const int pidx = t * HDIM + dd;
                    const float cc = pe_cos[pidx], ss = pe_sin[pidx], sc = pe_scale[pidx];
                    const float r = (dd & 1) ? (val * cc + partner * ss)
                                             : (val * cc - partner * ss);
                    val = (part == 0) ? (r * sc * QSCL) : (r / sc);
                    outp[(((size_t)bb * NHEADS + hh) * NT + t) * HDIM + dd] = f2h(val);
                }
            }
        } else {
            // v: sigma-permuted transpose. Thread (g,fr) holds keys
            // {nt=m, u=4g+j}; sigma = (m&1)*32 + 8g + (m>>1)*4 + j.
            // m=0,2 -> positions 8g+0..7 ; m=1,3 -> 32+8g+0..7.
            const int rowb = m0 + wr * 64;       // 64-aligned
            const int bb = rowb >> 11;
            const int tb = rowb & 2047;
            unsigned short* vp2 =
                &vtb[(((size_t)bb * NHEADS + hh) * HDIM + dd) * NT + tb];
            ushort4 s0a, s0b, s1a, s1b;
            s0a.x = f2h(acc[0][n][0] + bv); s0a.y = f2h(acc[0][n][1] + bv);
            s0a.z = f2h(acc[0][n][2] + bv); s0a.w = f2h(acc[0][n][3] + bv);
            s0b.x = f2h(acc[2][n][0] + bv); s0b.y = f2h(acc[2][n][1] + bv);
            s0b.z = f2h(acc[2][n][2] + bv); s0b.w = f2h(acc[2][n][3] + bv);
            s1a.x = f2h(acc[1][n][0] + bv); s1a.y = f2h(acc[1][n][1] + bv);
            s1a.z = f2h(acc[1][n][2] + bv); s1a.w = f2h(acc[1][n][3] + bv);
            s1b.x = f2h(acc[3][n][0] + bv); s1b.y = f2h(acc[3][n][1] + bv);
            s1b.z = f2h(acc[3][n][2] + bv); s1b.w = f2h(acc[3][n][3] + bv);
            *(ushort4*)&vp2[8 * g]          = s0a;
            *(ushort4*)&vp2[8 * g + 4]      = s0b;
            *(ushort4*)&vp2[32 + 8 * g]     = s1a;
            *(ushort4*)&vp2[32 + 8 * g + 4] = s1b;
        }
    }
}

// ---------------------------------------------------------------------------
// Kernel 2: flash attention, fp16 MFMA, SWAPPED QK^T (S^T = mfma(K,Q)) so
// each lane holds a full P fragment row in registers -> P never touches LDS.
// 1 block = (b,h,128 q-rows), 4 waves x 32 q-rows (M=2). K/Vt (sigma-order)
// double-buffered in LDS; defer-max with tile-wide mi; li per-lane scalar.
// ---------------------------------------------------------------------------
__global__ __launch_bounds__(256) void attn_mfma_kernel(
    const unsigned short* __restrict__ qb, const unsigned short* __restrict__ kb,
    const unsigned short* __restrict__ vtb, const unsigned short* __restrict__ m16,
    float* __restrict__ out)
{
    __shared__ __align__(16) unsigned short Ks[2][64 * 64];
    __shared__ __align__(16) unsigned short Vs[2][64 * 64];

    const int tid = threadIdx.x;
    const int w = tid >> 6, lane = tid & 63;
    const int g = lane >> 4, fr = lane & 15;

    const int bid = blockIdx.x;                  // 1024 blocks, XCD swizzle
    const int s = (bid & 7) * 128 + (bid >> 3);
    const int q0 = (s & 15) * 128;
    const int h = (s >> 4) & 15;
    const int b = s >> 8;

    const size_t bh = (size_t)b * NHEADS + h;
    const unsigned short* qp = qb + (bh * NT + q0 + w * 32) * HDIM;
    const unsigned short* kp = kb + bh * NT * HDIM;
    const unsigned short* vtp = vtb + bh * HDIM * NT;
    // mask row for this lane's query (q = m*16 + fr)
    const unsigned short* mp = m16 + ((size_t)b * NT + q0 + w * 32 + fr) * NT;

    const int sc0 = tid, sc1 = tid + 256;
    const int sr0 = sc0 >> 3, scb0 = ((sc0 & 7) * 16) ^ ((sr0 & 7) << 4);
    const int sr1 = sc1 >> 3, scb1 = ((sc1 & 7) * 16) ^ ((sr1 & 7) << 4);

#define STAGE(buf, kt)                                                          \
    do {                                                                        \
        const unsigned short* ktp_ = kp + (kt) * 64 * HDIM;                     \
        GLL16(ktp_ + sr0 * HDIM + (scb0 >> 1), (char*)Ks[buf] + sc0 * 16);      \
        GLL16(vtp + (size_t)sr0 * NT + (kt) * 64 + (scb0 >> 1),                 \
              (char*)Vs[buf] + sc0 * 16);                                       \
        GLL16(ktp_ + sr1 * HDIM + (scb1 >> 1), (char*)Ks[buf] + sc1 * 16);      \
        GLL16(vtp + (size_t)sr1 * NT + (kt) * 64 + (scb1 >> 1),                 \
              (char*)Vs[buf] + sc1 * 16);                                       \
    } while (0)

    half8v qf[2][2];
#pragma unroll
    for (int m = 0; m < 2; ++m)
#pragma unroll
        for (int kk = 0; kk < 2; ++kk)
            qf[m][kk] = *(const half8v*)(qp + (m * 16 + fr) * HDIM + kk * 32 + g * 8);

    f32x4 acc[2][4];
    float li[2], mi[2];
#pragma unroll
    for (int m = 0; m < 2; ++m) {
        li[m] = 0.f; mi[m] = -3.0e38f;
#pragma unroll
        for (int dt = 0; dt < 4; ++dt) acc[m][dt] = (f32x4){0.f, 0.f, 0.f, 0.f};
    }
    const float THR = 11.541560327111708f;   // 8 * log2e

    STAGE(0, 0);
    __syncthreads();
    int cur = 0;

    for (int kt = 0; kt < NT / 64; ++kt) {
        if (kt + 1 < NT / 64) STAGE(cur ^ 1, kt + 1);

        // K and V fragments once per tile, reused by both m-tiles
        half8v kf[4][2], vf[4][2];
#pragma unroll
        for (int nt = 0; nt < 4; ++nt) {
            const int r = nt * 16 + fr;
#pragma unroll
            for (int kk = 0; kk < 2; ++kk) {
                const int off = r * 128 + ((kk * 64 + g * 16) ^ ((r & 7) << 4));
                kf[nt][kk] = *(const half8v*)((const char*)Ks[cur] + off);
                vf[nt][kk] = *(const half8v*)((const char*)Vs[cur] + off);
            }
        }

#pragma unroll
        for (int m = 0; m < 2; ++m) {
            // S^T = K Q^T : lane (g,fr) -> query fr, keys nt*16 + 4g + j
            f32x4 Sm[4];
#pragma unroll
            for (int nt = 0; nt < 4; ++nt) {
                Sm[nt] = (f32x4){0.f, 0.f, 0.f, 0.f};
#pragma unroll
                for (int kk = 0; kk < 2; ++kk)
                    Sm[nt] = __builtin_amdgcn_mfma_f32_16x16x32_f16(kf[nt][kk], qf[m][kk], Sm[nt], 0, 0, 0);
            }

            float sv[4][4];
            float smax = -3.4e38f;
            const unsigned short* mq = mp + (size_t)m * 16 * NT + kt * 64;
#pragma unroll
            for (int nt = 0; nt < 4; ++nt) {
                const ushort4 mv = *(const ushort4*)(mq + nt * 16 + 4 * g);
                sv[nt][0] = Sm[nt][0] + h2f(mv.x);
                sv[nt][1] = Sm[nt][1] + h2f(mv.y);
                sv[nt][2] = Sm[nt][2] + h2f(mv.z);
                sv[nt][3] = Sm[nt][3] + h2f(mv.w);
                smax = fmaxf(smax,
                             fmaxf(fmaxf(sv[nt][0], sv[nt][1]),
                                   fmaxf(sv[nt][2], sv[nt][3])));
            }

            // defer-max: mi[m] tile-wide; full-wave reduce only on threat
            if (!__all(smax - mi[m] <= THR)) {
                float rm = smax;
                rm = fmaxf(rm, __shfl_xor(rm, 1, 64));
                rm = fmaxf(rm, __shfl_xor(rm, 2, 64));
                rm = fmaxf(rm, __shfl_xor(rm, 4, 64));
                rm = fmaxf(rm, __shfl_xor(rm, 8, 64));
                rm = fmaxf(rm, __shfl_xor(rm, 16, 64));
                rm = fmaxf(rm, __shfl_xor(rm, 32, 64));
                const float mnew = fmaxf(mi[m], rm);
                const float alpha = exp2fast(mi[m] - mnew);
                li[m] *= alpha;
#pragma unroll
                for (int dt = 0; dt < 4; ++dt) acc[m][dt] *= alpha;
                mi[m] = mnew;
            }

            // P in registers; assemble PV A-fragments directly.
            float p[4][4];
            float ps = 0.f;
#pragma unroll
            for (int nt = 0; nt < 4; ++nt)
#pragma unroll
                for (int j = 0; j < 4; ++j) {
                    p[nt][j] = exp2fast(sv[nt][j] - mi[m]);
                    ps += p[nt][j];
                }
            li[m] += ps;
            u32x4 u0, u1;
            u0.x = pack2h(p[0][0], p[0][1]); u0.y = pack2h(p[0][2], p[0][3]);
            u0.z = pack2h(p[2][0], p[2][1]); u0.w = pack2h(p[2][2], p[2][3]);
            u1.x = pack2h(p[1][0], p[1][1]); u1.y = pack2h(p[1][2], p[1][3]);
            u1.z = pack2h(p[3][0], p[3][1]); u1.w = pack2h(p[3][2], p[3][3]);
            const half8v pf0 = __builtin_bit_cast(half8v, u0);
            const half8v pf1 = __builtin_bit_cast(half8v, u1);

#pragma unroll
            for (int dt = 0; dt < 4; ++dt) {
                acc[m][dt] = __builtin_amdgcn_mfma_f32_16x16x32_f16(pf0, vf[dt][0], acc[m][dt], 0, 0, 0);
                acc[m][dt] = __builtin_amdgcn_mfma_f32_16x16x32_f16(pf1, vf[dt][1], acc[m][dt], 0, 0, 0);
            }
        }

        __syncthreads();
        cur ^= 1;
    }

    // li: sum across the 4 g-lanes holding the same query (xor 16, 32),
    // then redistribute to the acc layout (row q = 4g+j) via shfl.
#pragma unroll
    for (int m = 0; m < 2; ++m) {
        float lt = li[m];
        lt += __shfl_xor(lt, 16, 64);
        lt += __shfl_xor(lt, 32, 64);
#pragma unroll
        for (int j = 0; j < 4; ++j) {
            const float lq = __shfl(lt, 4 * g + j, 64);
            const float inv = 1.f / lq;
            const int t = q0 + w * 32 + m * 16 + 4 * g + j;
            float* op = out + (((size_t)b * NT + t) * NHEADS + h) * HDIM;
#pragma unroll
            for (int dt = 0; dt < 4; ++dt) op[dt * 16 + fr] = acc[m][dt][j] * inv;
        }
    }
}

extern "C" void kernel_launch(void* const* d_in, const int* in_sizes, int n_in,
                              void* d_out, int out_size, void* d_ws, size_t ws_size,
                              hipStream_t stream) {
    const float* x        = (const float*)d_in[0];
    const float* pe_cos   = (const float*)d_in[1];
    const float* pe_sin   = (const float*)d_in[2];
    const float* pe_scale = (const float*)d_in[3];
    const float* mask     = (const float*)d_in[4];
    const float* w_qkv    = (const float*)d_in[5];
    const float* b_qkv    = (const float*)d_in[6];
    float* out = (float*)d_out;

    unsigned short* ws = (unsigned short*)d_ws;
    const size_t PER = (size_t)NB * NHEADS * NT * HDIM;   // 8388608
    unsigned short* qbuf = ws;
    unsigned short* kbuf = ws + PER;
    unsigned short* vtbuf = ws + 2 * PER;
    unsigned short* xbuf = ws + 3 * PER;                  // fp16 x (GEMM only)
    unsigned short* wbuf = xbuf + (size_t)NB * NT * NC;   // fp16 w (GEMM only)
    unsigned short* maskbuf = ws + 3 * PER;               // fp16 mask (after GEMM)

    conv_f16_kernel<<<8192, 256, 0, stream>>>(x, xbuf, (NB * NT * NC) / 4, 1.0f);
    conv_f16_kernel<<<3072, 256, 0, stream>>>(w_qkv, wbuf, (3 * NC * NC) / 4, 1.0f);
    qkv_gemm_kernel<<<1536, 256, 0, stream>>>(xbuf, wbuf, b_qkv,
                                              pe_cos, pe_sin, pe_scale,
                                              qbuf, kbuf, vtbuf);
    conv_f16_kernel<<<16384, 256, 0, stream>>>(mask, maskbuf, (NB * NT * NT) / 4, LOG2E);
    attn_mfma_kernel<<<1024, 256, 0, stream>>>(qbuf, kbuf, vtbuf, maskbuf, out);
}

// Round 14
// 254.473 us; speedup vs baseline: 1.3631x; 1.0648x over previous
//
#include <hip/hip_runtime.h>
#include <math.h>

#define NB 4
#define NT 2048
#define NC 1024
#define NHEADS 16
#define HDIM 64

typedef __attribute__((ext_vector_type(8))) _Float16 half8v;
typedef __attribute__((ext_vector_type(2))) __fp16 fp16x2;
typedef __attribute__((ext_vector_type(4))) float f32x4;

#define LOG2E 1.4426950408889634f

__device__ inline unsigned short f2h(float f) {
    _Float16 h = (_Float16)f;
    return __builtin_bit_cast(unsigned short, h);
}
__device__ inline float h2f(unsigned short u) {
    return (float)__builtin_bit_cast(_Float16, u);
}
__device__ inline float exp2fast(float x) {
#if __has_builtin(__builtin_amdgcn_exp2f)
    return __builtin_amdgcn_exp2f(x);
#else
    return exp2f(x);
#endif
}
__device__ inline unsigned int pack2h(float a, float b) {
    fp16x2 p = __builtin_amdgcn_cvt_pkrtz(a, b);
    return __builtin_bit_cast(unsigned int, p);
}

#define AS1C(p) ((const __attribute__((address_space(1))) unsigned int*)(unsigned long long)(const void*)(p))
#define AS3P(p) ((__attribute__((address_space(3))) unsigned int*)(unsigned int)(unsigned long long)(void*)(p))
#define GLL16(gp, lp) __builtin_amdgcn_global_load_lds(AS1C(gp), AS3P(lp), 16, 0, 0)

// ---------------------------------------------------------------------------
// fp32 -> fp16 convert (vectorized)
// ---------------------------------------------------------------------------
__global__ __launch_bounds__(256) void conv_f16_kernel(
    const float* __restrict__ in, unsigned short* __restrict__ out, int n4)
{
    const int i = blockIdx.x * 256 + threadIdx.x;
    if (i >= n4) return;
    const float4 f = ((const float4*)in)[i];
    ushort4 h;
    h.x = f2h(f.x); h.y = f2h(f.y); h.z = f2h(f.z); h.w = f2h(f.w);
    ((ushort4*)out)[i] = h;
}

// ---------------------------------------------------------------------------
// mask fp32 -> fp16 * log2e, permuted into MFMA fragment order per 64-col
// block: out[row][kt*64 + fr*4 + nt] = in[row][kt*64 + nt*16 + fr] * log2e
// ---------------------------------------------------------------------------
__global__ __launch_bounds__(256) void mask_conv_kernel(
    const float* __restrict__ in, unsigned short* __restrict__ out)
{
    const size_t i = (size_t)blockIdx.x * 256 + threadIdx.x;  // ushort4 index
    const int row = (int)(i >> 9);
    const int c4 = (int)(i & 511);
    const int ktb = c4 >> 4;
    const int fr = c4 & 15;
    const float* ip = in + (size_t)row * NT + ktb * 64 + fr;
    ushort4 o;
    o.x = f2h(ip[0] * LOG2E);
    o.y = f2h(ip[16] * LOG2E);
    o.z = f2h(ip[32] * LOG2E);
    o.w = f2h(ip[48] * LOG2E);
    ((ushort4*)out)[i] = o;
}

// ---------------------------------------------------------------------------
// Kernel 1: qkv = x @ w^T + b via fp16 MFMA, fused RoPE.
// q written fp16 (B,NH,T,D) PRE-SCALED by scl*log2e; k fp16 (B,NH,T,D);
// v written TRANSPOSED+key-PERMUTED fp16: vt2[b][h][d][(t&~63) + pi(t&63)]
// with pi(nt*16+fr) = fr*4+nt, matching attention's P/V k-ordering.
// ---------------------------------------------------------------------------
__global__ __launch_bounds__(256) void qkv_gemm_kernel(
    const unsigned short* __restrict__ xf, const unsigned short* __restrict__ wf,
    const float* __restrict__ bias, const float* __restrict__ pe_cos,
    const float* __restrict__ pe_sin, const float* __restrict__ pe_scale,
    unsigned short* __restrict__ qb, unsigned short* __restrict__ kb,
    unsigned short* __restrict__ vtb)
{
    __shared__ __align__(16) unsigned short Ah[128 * 32];
    __shared__ __align__(16) unsigned short Bh[128 * 32];

    const int tid = threadIdx.x;
    const int w = tid >> 6, lane = tid & 63;
    const int g = lane >> 4, fr = lane & 15;
    const int wr = w >> 1, wc = w & 1;

    const int bid = blockIdx.x;                 // 1536 blocks, XCD swizzle
    const int s = (bid & 7) * 192 + (bid >> 3);
    const int m0 = (s & 63) * 128, n0 = (s >> 6) * 128;

    const int c0 = tid, c1 = tid + 256;
    const int r0 = c0 >> 2, r1 = c1 >> 2;
    const int cb0 = ((c0 & 3) * 16) ^ (((r0 >> 1) & 3) << 4);
    const int cb1 = ((c1 & 3) * 16) ^ (((r1 >> 1) & 3) << 4);
    const unsigned short* px0 = xf + (size_t)(m0 + r0) * NC + (cb0 >> 1);
    const unsigned short* px1 = xf + (size_t)(m0 + r1) * NC + (cb1 >> 1);
    const unsigned short* pw0 = wf + (size_t)(n0 + r0) * NC + (cb0 >> 1);
    const unsigned short* pw1 = wf + (size_t)(n0 + r1) * NC + (cb1 >> 1);

    f32x4 acc[4][4];
#pragma unroll
    for (int m = 0; m < 4; ++m)
#pragma unroll
        for (int n = 0; n < 4; ++n) acc[m][n] = (f32x4){0.f, 0.f, 0.f, 0.f};

    for (int k0 = 0; k0 < NC; k0 += 32) {
        __syncthreads();
        GLL16(px0 + k0, (char*)Ah + c0 * 16);
        GLL16(px1 + k0, (char*)Ah + c1 * 16);
        GLL16(pw0 + k0, (char*)Bh + c0 * 16);
        GLL16(pw1 + k0, (char*)Bh + c1 * 16);
        __syncthreads();

        half8v a_f[4], b_f[4];
#pragma unroll
        for (int m = 0; m < 4; ++m) {
            const int r = wr * 64 + m * 16 + fr;
            const int off = r * 64 + ((g * 16) ^ (((r >> 1) & 3) << 4));
            a_f[m] = *(const half8v*)((const char*)Ah + off);
        }
#pragma unroll
        for (int n = 0; n < 4; ++n) {
            const int r = wc * 64 + n * 16 + fr;
            const int off = r * 64 + ((g * 16) ^ (((r >> 1) & 3) << 4));
            b_f[n] = *(const half8v*)((const char*)Bh + off);
        }
#pragma unroll
        for (int m = 0; m < 4; ++m)
#pragma unroll
            for (int n = 0; n < 4; ++n)
                acc[m][n] = __builtin_amdgcn_mfma_f32_16x16x32_f16(a_f[m], b_f[n], acc[m][n], 0, 0, 0);
    }

    // Epilogue: bias + RoPE (+*scale*scl*log2e q, /scale k), scatter.
    const float QSCL = 0.08838834764831845f * LOG2E;  // 1/sqrt(2*D) * log2e
#pragma unroll
    for (int n = 0; n < 4; ++n) {
        const int col = n0 + wc * 64 + n * 16 + fr;
        const int part = col >> 10;             // wave-uniform (16-col span)
        const int hh = (col & 1023) >> 6;
        const int dd = col & 63;
        const float bv = bias[col];
        if (part < 2) {
            unsigned short* outp = (part == 0) ? qb : kb;
#pragma unroll
            for (int m = 0; m < 4; ++m) {
                const int row0 = m0 + wr * 64 + m * 16 + 4 * g;
                const int bb = row0 >> 11;
                const int t0 = row0 & 2047;
#pragma unroll
                for (int j = 0; j < 4; ++j) {
                    const int t = t0 + j;
                    float val = acc[m][n][j] + bv;
                    const float partner = __shfl_xor(val, 1, 64);
                    const int pidx = t * HDIM + dd;
                    const float cc = pe_cos[pidx], ss = pe_sin[pidx], sc = pe_scale[pidx];
                    const float r = (dd & 1) ? (val * cc + partner * ss)
                                             : (val * cc - partner * ss);
                    val = (part == 0) ? (r * sc * QSCL) : (r / sc);
                    outp[(((size_t)bb * NHEADS + hh) * NT + t) * HDIM + dd] = f2h(val);
                }
            }
        } else {
            // v: key-permuted transpose. Thread holds keys {nt=m, fr'=4g+j}
            // across m -> pos (4g+j)*4 + m are 4 consecutive -> ushort4.
            const int rowb = m0 + wr * 64;       // 64-aligned
            const int bb = rowb >> 11;
            const int tb = rowb & 2047;
            unsigned short* vp2 =
                &vtb[(((size_t)bb * NHEADS + hh) * HDIM + dd) * NT + tb];
#pragma unroll
            for (int j = 0; j < 4; ++j) {
                ushort4 sv;
                sv.x = f2h(acc[0][n][j] + bv);
                sv.y = f2h(acc[1][n][j] + bv);
                sv.z = f2h(acc[2][n][j] + bv);
                sv.w = f2h(acc[3][n][j] + bv);
                *(ushort4*)&vp2[(4 * g + j) * 4] = sv;
            }
        }
    }
}

// ---------------------------------------------------------------------------
// Kernel 2: flash attention, fp16 MFMA. Round-10 structure (best measured)
// + cross-iteration mask REGISTER PREFETCH: tile kt+1's mask quads are
// loaded where STAGE(kt+1) is issued, a full compute phase + barrier before
// use, hiding L2 latency the compiler cannot hoist across s_barrier.
// ---------------------------------------------------------------------------
__global__ __launch_bounds__(256) void attn_mfma_kernel(
    const unsigned short* __restrict__ qb, const unsigned short* __restrict__ kb,
    const unsigned short* __restrict__ vtb, const unsigned short* __restrict__ m16,
    float* __restrict__ out)
{
    __shared__ __align__(16) unsigned short Ks[2][64 * 64];
    __shared__ __align__(16) unsigned short Vs[2][64 * 64];
    __shared__ __align__(16) unsigned short Ps[4][32 * 64];

    const int tid = threadIdx.x;
    const int w = tid >> 6, lane = tid & 63;
    const int g = lane >> 4, fr = lane & 15;

    const int bid = blockIdx.x;                  // 1024 blocks, XCD swizzle
    const int s = (bid & 7) * 128 + (bid >> 3);
    const int q0 = (s & 15) * 128;
    const int h = (s >> 4) & 15;
    const int b = s >> 8;

    const size_t bh = (size_t)b * NHEADS + h;
    const unsigned short* qp = qb + (bh * NT + q0 + w * 32) * HDIM;
    const unsigned short* kp = kb + bh * NT * HDIM;
    const unsigned short* vtp = vtb + bh * HDIM * NT;
    const unsigned short* mp = m16 + ((size_t)b * NT + q0 + w * 32) * NT;

    const int sc0 = tid, sc1 = tid + 256;
    const int sr0 = sc0 >> 3, scb0 = ((sc0 & 7) * 16) ^ ((sr0 & 7) << 4);
    const int sr1 = sc1 >> 3, scb1 = ((sc1 & 7) * 16) ^ ((sr1 & 7) << 4);

#define STAGE(buf, kt)                                                          \
    do {                                                                        \
        const unsigned short* ktp_ = kp + (kt) * 64 * HDIM;                     \
        GLL16(ktp_ + sr0 * HDIM + (scb0 >> 1), (char*)Ks[buf] + sc0 * 16);      \
        GLL16(vtp + (size_t)sr0 * NT + (kt) * 64 + (scb0 >> 1),                 \
              (char*)Vs[buf] + sc0 * 16);                                       \
        GLL16(ktp_ + sr1 * HDIM + (scb1 >> 1), (char*)Ks[buf] + sc1 * 16);      \
        GLL16(vtp + (size_t)sr1 * NT + (kt) * 64 + (scb1 >> 1),                 \
              (char*)Vs[buf] + sc1 * 16);                                       \
    } while (0)

#define MLOAD(dst, kt)                                                          \
    do {                                                                        \
        _Pragma("unroll")                                                       \
        for (int m_ = 0; m_ < 2; ++m_) {                                        \
            _Pragma("unroll")                                                   \
            for (int j_ = 0; j_ < 4; ++j_)                                      \
                dst[m_][j_] = *(const ushort4*)(                                \
                    mp + (size_t)(m_ * 16 + 4 * g + j_) * NT + (kt) * 64 + fr * 4); \
        }                                                                       \
    } while (0)

    half8v qf[2][2];
#pragma unroll
    for (int m = 0; m < 2; ++m)
#pragma unroll
        for (int kk = 0; kk < 2; ++kk)
            qf[m][kk] = *(const half8v*)(qp + (m * 16 + fr) * HDIM + kk * 32 + g * 8);

    f32x4 acc[2][4];
    float li[2][4], mi[2][4];
#pragma unroll
    for (int m = 0; m < 2; ++m)
#pragma unroll
        for (int j = 0; j < 4; ++j) {
            li[m][j] = 0.f; mi[m][j] = -3.0e38f;
            acc[m][j] = (f32x4){0.f, 0.f, 0.f, 0.f};
        }
    const float THR = 11.541560327111708f;   // 8 * log2e

    ushort4 mcur[2][4], mnxt[2][4];
    MLOAD(mcur, 0);
    STAGE(0, 0);
    __syncthreads();
    int cur = 0;

    for (int kt = 0; kt < NT / 64; ++kt) {
        if (kt + 1 < NT / 64) {
            STAGE(cur ^ 1, kt + 1);
            MLOAD(mnxt, kt + 1);
        }

        half8v kf[4][2];
#pragma unroll
        for (int nt = 0; nt < 4; ++nt) {
            const int r = nt * 16 + fr;
#pragma unroll
            for (int kk = 0; kk < 2; ++kk) {
                const int off = r * 128 + ((kk * 64 + g * 16) ^ ((r & 7) << 4));
                kf[nt][kk] = *(const half8v*)((const char*)Ks[cur] + off);
            }
        }

#pragma unroll
        for (int m = 0; m < 2; ++m) {
            f32x4 Sm[4];
#pragma unroll
            for (int nt = 0; nt < 4; ++nt) {
                Sm[nt] = (f32x4){0.f, 0.f, 0.f, 0.f};
#pragma unroll
                for (int kk = 0; kk < 2; ++kk)
                    Sm[nt] = __builtin_amdgcn_mfma_f32_16x16x32_f16(qf[m][kk], kf[nt][kk], Sm[nt], 0, 0, 0);
            }

            float sv[4][4], rmj[4];
#pragma unroll
            for (int j = 0; j < 4; ++j) {
                const ushort4 mv = mcur[m][j];
                sv[j][0] = Sm[0][j] + h2f(mv.x);
                sv[j][1] = Sm[1][j] + h2f(mv.y);
                sv[j][2] = Sm[2][j] + h2f(mv.z);
                sv[j][3] = Sm[3][j] + h2f(mv.w);
                rmj[j] = fmaxf(fmaxf(sv[j][0], sv[j][1]), fmaxf(sv[j][2], sv[j][3]));
            }

            const float worst = fmaxf(fmaxf(rmj[0] - mi[m][0], rmj[1] - mi[m][1]),
                                      fmaxf(rmj[2] - mi[m][2], rmj[3] - mi[m][3]));
            if (!__all(worst <= THR)) {
#pragma unroll
                for (int j = 0; j < 4; ++j) {
                    float rm = rmj[j];
                    rm = fmaxf(rm, __shfl_xor(rm, 1, 64));
                    rm = fmaxf(rm, __shfl_xor(rm, 2, 64));
                    rm = fmaxf(rm, __shfl_xor(rm, 4, 64));
                    rm = fmaxf(rm, __shfl_xor(rm, 8, 64));
                    const float mnew = fmaxf(mi[m][j], rm);
                    const float alpha = exp2fast(mi[m][j] - mnew);
                    li[m][j] *= alpha;
#pragma unroll
                    for (int dt = 0; dt < 4; ++dt) acc[m][dt][j] *= alpha;
                    mi[m][j] = mnew;
                }
            }

#pragma unroll
            for (int j = 0; j < 4; ++j) {
                const int prow = m * 16 + 4 * g + j;
                const float p0 = exp2fast(sv[j][0] - mi[m][j]);
                const float p1 = exp2fast(sv[j][1] - mi[m][j]);
                const float p2 = exp2fast(sv[j][2] - mi[m][j]);
                const float p3 = exp2fast(sv[j][3] - mi[m][j]);
                li[m][j] += (p0 + p1) + (p2 + p3);
                uint2 pw2;
                pw2.x = pack2h(p0, p1);
                pw2.y = pack2h(p2, p3);
                const int off = prow * 128 + ((fr * 8) ^ ((prow & 7) << 4));
                *(uint2*)((char*)Ps[w] + off) = pw2;
            }
        }

        half8v vf[4][2];
#pragma unroll
        for (int dt = 0; dt < 4; ++dt) {
            const int d = dt * 16 + fr;
#pragma unroll
            for (int kk = 0; kk < 2; ++kk) {
                const int off = d * 128 + ((kk * 64 + g * 16) ^ ((d & 7) << 4));
                vf[dt][kk] = *(const half8v*)((const char*)Vs[cur] + off);
            }
        }
#pragma unroll
        for (int m = 0; m < 2; ++m) {
            half8v pf[2];
#pragma unroll
            for (int kk = 0; kk < 2; ++kk) {
                const int off = (m * 16 + fr) * 128 + ((kk * 64 + g * 16) ^ ((fr & 7) << 4));
                pf[kk] = *(const half8v*)((const char*)Ps[w] + off);
            }
#pragma unroll
            for (int dt = 0; dt < 4; ++dt)
#pragma unroll
                for (int kk = 0; kk < 2; ++kk)
                    acc[m][dt] = __builtin_amdgcn_mfma_f32_16x16x32_f16(pf[kk], vf[dt][kk], acc[m][dt], 0, 0, 0);
        }

        __syncthreads();
        cur ^= 1;
#pragma unroll
        for (int m = 0; m < 2; ++m)
#pragma unroll
            for (int j = 0; j < 4; ++j) mcur[m][j] = mnxt[m][j];
    }

#pragma unroll
    for (int m = 0; m < 2; ++m)
#pragma unroll
        for (int j = 0; j < 4; ++j) {
            float lt = li[m][j];
            lt += __shfl_xor(lt, 1, 64);
            lt += __shfl_xor(lt, 2, 64);
            lt += __shfl_xor(lt, 4, 64);
            lt += __shfl_xor(lt, 8, 64);
            const float inv = 1.f / lt;
            const int t = q0 + w * 32 + m * 16 + 4 * g + j;
            float* op = out + (((size_t)b * NT + t) * NHEADS + h) * HDIM;
#pragma unroll
            for (int dt = 0; dt < 4; ++dt) op[dt * 16 + fr] = acc[m][dt][j] * inv;
        }
}

extern "C" void kernel_launch(void* const* d_in, const int* in_sizes, int n_in,
                              void* d_out, int out_size, void* d_ws, size_t ws_size,
                              hipStream_t stream) {
    const float* x        = (const float*)d_in[0];
    const float* pe_cos   = (const float*)d_in[1];
    const float* pe_sin   = (const float*)d_in[2];
    const float* pe_scale = (const float*)d_in[3];
    const float* mask     = (const float*)d_in[4];
    const float* w_qkv    = (const float*)d_in[5];
    const float* b_qkv    = (const float*)d_in[6];
    float* out = (float*)d_out;

    unsigned short* ws = (unsigned short*)d_ws;
    const size_t PER = (size_t)NB * NHEADS * NT * HDIM;   // 8388608
    unsigned short* qbuf = ws;
    unsigned short* kbuf = ws + PER;
    unsigned short* vtbuf = ws + 2 * PER;
    unsigned short* xbuf = ws + 3 * PER;                  // fp16 x (GEMM only)
    unsigned short* wbuf = xbuf + (size_t)NB * NT * NC;   // fp16 w (GEMM only)
    unsigned short* maskbuf = ws + 3 * PER;               // fp16 mask (after GEMM)

    conv_f16_kernel<<<8192, 256, 0, stream>>>(x, xbuf, (NB * NT * NC) / 4);
    conv_f16_kernel<<<3072, 256, 0, stream>>>(w_qkv, wbuf, (3 * NC * NC) / 4);
    qkv_gemm_kernel<<<1536, 256, 0, stream>>>(xbuf, wbuf, b_qkv,
                                              pe_cos, pe_sin, pe_scale,
                                              qbuf, kbuf, vtbuf);
    mask_conv_kernel<<<16384, 256, 0, stream>>>(mask, maskbuf);
    attn_mfma_kernel<<<1024, 256, 0, stream>>>(qbuf, kbuf, vtbuf, maskbuf, out);
}